// Round 8
// baseline (110.511 us; speedup 1.0000x reference)
//
#include <hip/hip_runtime.h>
#include <stdint.h>

// FibonacciKAN: y[b,o] = sum_i sum_d F_d(tanh(x[b,i])) * C[i,o,d]
// => y = bias[o] + sum_i (t*W0 + t^2*W1 + t^3*W2 + t^4*W3)[i,o]
// GEMM: M=32768, N=256, K=1024, bf16 MFMA 16x16x32.
//
// R8: mt 4 -> 8. R4/R6/R7 all shared mt=4 and all pinned at ~45us /
// MfmaUtil ~14%: B-frag supply (1024/mt B per MFMA, ~211 B/cyc/CU demand,
// effective supply ~31 B/cyc) is the invariant wall; wave count doesn't
// change it. mt=8 halves B demand -> predicted util ~29%, gemm ~23us.
// Wave tile 128x32 (mt=8, nt=2, acc=64), block 128x128 (4 waves), grid 512
// = 2 blocks/CU, LDS 66.5KB (133/CU), 2 w/SIMD. MFMA order + roundings
// unchanged -> absmax 9.766e-4.

typedef short bf16x8 __attribute__((ext_vector_type(8)));
typedef float f32x4 __attribute__((ext_vector_type(4)));
typedef unsigned int uint4v __attribute__((ext_vector_type(4)));

__device__ __forceinline__ unsigned int pack_bf16_trunc(float a, float b) {
  return __builtin_amdgcn_perm(__float_as_uint(b), __float_as_uint(a), 0x07060302u);
}
__device__ __forceinline__ unsigned int round_bf16_bits(float a) {
  unsigned int u = __float_as_uint(a);
  return u + 0x7fffu + ((u >> 16) & 1u);
}
__device__ __forceinline__ unsigned int pack_bf16_rne(float a, float b) {
  return __builtin_amdgcn_perm(round_bf16_bits(b), round_bf16_bits(a), 0x07060302u);
}
__device__ __forceinline__ float fast_tanh(float x) {
  float e = exp2f(x * 2.8853900817779268f);  // 2*log2(e)
  return 1.0f - 2.0f * __builtin_amdgcn_rcpf(e + 1.0f);
}

// ---------------- prep (unchanged) ----------------
__global__ void prep_kernel(const float* __restrict__ C, short* __restrict__ Bp,
                            float* __restrict__ bias) {
  int b = blockIdx.x;
  if (b < 256) {
    int i = b;
    int n = threadIdx.x;
    const float* c = C + (i * 256 + n) * 6;
    float c2 = c[2], c3 = c[3], c4_ = c[4], c5 = c[5];
    float w0 = c2 + 2.0f * c4_;
    float w1 = c3 + 3.0f * c5;
    unsigned int r0 = pack_bf16_rne(w0, w1);
    unsigned int r1 = pack_bf16_rne(c4_, c5);
    int ks = i >> 3;
    int lane = (((i >> 1) & 3) << 4) | (n & 15);
    int ntg = n >> 4;
    int off = (((ks * 16 + ntg) * 64 + lane) << 3) + ((i & 1) << 2);
    *(uint2*)(Bp + off) = make_uint2(r0, r1);
  } else {
    int w = threadIdx.x >> 6;
    int t = threadIdx.x & 63;
    int n = (b - 256) * 4 + w;
    float s = 0.0f;
#pragma unroll
    for (int r = 0; r < 4; ++r) {
      int i = t + r * 64;
      const float* c = C + (i * 256 + n) * 6;
      s += c[1] + c[3] + c[5];
    }
#pragma unroll
    for (int off = 32; off > 0; off >>= 1) s += __shfl_down(s, off);
    if (t == 0) bias[n] = s;
  }
}

// ---------------- fused tanh + powers + GEMM ----------------
// Block: 128 rows x 128 cols (n-half nb), 256 thr = 4 waves; wave wv owns a
// 32-col group. Wave tile 128x32 = mt8 x nt2. Grid 512 = 2 blocks/CU.
__global__ __launch_bounds__(256, 2) void fibkan_gemm(
    const float* __restrict__ x, const short* __restrict__ Bp,
    const float* __restrict__ bias, float* __restrict__ y) {
  __shared__ unsigned short tl[128 * 260];  // 66560 B -> 2 blocks/CU
  const int tid = threadIdx.x;
  const int lane = tid & 63;
  const int wv = tid >> 6;                 // 32-col group within n-half
  const int mb = blockIdx.x >> 1, nb = blockIdx.x & 1;
  const int lhi = lane >> 4, llo = lane & 15;

  const float4* xp = (const float4*)(x) + mb * 128 * 64;  // x row = 64 float4

  float bv[2];
#pragma unroll
  for (int nt = 0; nt < 2; ++nt)
    bv[nt] = bias[nb * 128 + wv * 32 + nt * 16 + llo];

  // ---- stage t = tanh(x): 128 rows x 256 cols ----
#pragma unroll
  for (int it = 0; it < 32; ++it) {
    int j = tid + it * 256;           // float4 index 0..8191
    int row = j >> 6, c = j & 63;
    float4 v = xp[row * 64 + c];
    uint2 pk = make_uint2(pack_bf16_rne(fast_tanh(v.x), fast_tanh(v.y)),
                          pack_bf16_rne(fast_tanh(v.z), fast_tanh(v.w)));
    *(uint2*)&tl[row * 260 + c * 4] = pk;
  }
  __syncthreads();

  // t u32 for (mt, ks): tp0 + mt*16*260 + ks*8 (shorts)
  const unsigned short* tp0 = &tl[llo * 260 + lhi * 2];
  // B-frag (ks, nt): bp[ks*1024 + nt*64]
  const bf16x8* bp = (const bf16x8*)Bp + (nb * 8 + wv * 2) * 64 + lane;

  f32x4 acc[8][2] = {};
  unsigned int tA[2][8];
  bf16x8 bB[2][2];
#pragma unroll
  for (int p = 0; p < 2; ++p) {
#pragma unroll
    for (int mt = 0; mt < 8; ++mt)
      tA[p][mt] = *(const unsigned int*)(tp0 + mt * 16 * 260 + p * 8);
#pragma unroll
    for (int nt = 0; nt < 2; ++nt) bB[p][nt] = bp[p * 1024 + nt * 64];
  }

  auto halfstep = [&](int ks, int p, bool pf) {
    bf16x8 af[8];
#pragma unroll
    for (int mt = 0; mt < 8; ++mt) {
      unsigned int tp2 = tA[p][mt];
      float ta = __uint_as_float(tp2 << 16);
      float tb = __uint_as_float(tp2 & 0xffff0000u);
      float ta2 = ta * ta, tb2 = tb * tb;
      float ta3 = ta2 * ta, tb3 = tb2 * tb;
      float ta4 = ta2 * ta2, tb4 = tb2 * tb2;
      uint4v u = {pack_bf16_trunc(ta, ta2), pack_bf16_trunc(ta3, ta4),
                  pack_bf16_trunc(tb, tb2), pack_bf16_trunc(tb3, tb4)};
      af[mt] = __builtin_bit_cast(bf16x8, u);
    }
#pragma unroll
    for (int nt = 0; nt < 2; ++nt) {
#pragma unroll
      for (int mt = 0; mt < 8; ++mt) {
        acc[mt][nt] = __builtin_amdgcn_mfma_f32_16x16x32_bf16(
            af[mt], bB[p][nt], acc[mt][nt], 0, 0, 0);
      }
    }
    if (pf) {
#pragma unroll
      for (int nt = 0; nt < 2; ++nt) bB[p][nt] = bp[(ks + 2) * 1024 + nt * 64];
#pragma unroll
      for (int mt = 0; mt < 8; ++mt)
        tA[p][mt] = *(const unsigned int*)(tp0 + mt * 16 * 260 + (ks + 2) * 8);
    }
  };

  for (int ks2 = 0; ks2 < 15; ++ks2) {
    halfstep(2 * ks2, 0, true);
    halfstep(2 * ks2 + 1, 1, true);
  }
  halfstep(30, 0, false);
  halfstep(31, 1, false);

  // epilogue: D col = nb*128 + wv*32 + nt*16 + llo, row = mt*16 + lhi*4 + r
  const int col0 = nb * 128 + wv * 32 + llo;
  const int row0 = mb * 128 + lhi * 4;
#pragma unroll
  for (int nt = 0; nt < 2; ++nt) {
#pragma unroll
    for (int mt = 0; mt < 8; ++mt) {
#pragma unroll
      for (int r = 0; r < 4; ++r) {
        y[(row0 + mt * 16 + r) * 256 + col0 + nt * 16] = acc[mt][nt][r] + bv[nt];
      }
    }
  }
}

extern "C" void kernel_launch(void* const* d_in, const int* in_sizes, int n_in,
                              void* d_out, int out_size, void* d_ws, size_t ws_size,
                              hipStream_t stream) {
  const float* x = (const float*)d_in[0];        // [32768, 256] f32
  const float* C = (const float*)d_in[1];        // [256, 256, 6] f32
  float* y = (float*)d_out;                      // [32768, 256] f32
  float* bias = (float*)d_ws;                    // 256 f32
  short* Bp = (short*)((char*)d_ws + 1024);      // 1024x256 bf16, frag-ordered
  prep_kernel<<<320, 256, 0, stream>>>(C, Bp, bias);
  fibkan_gemm<<<512, 256, 0, stream>>>(x, Bp, bias, y);
}

// Round 9
// 104.890 us; speedup vs baseline: 1.0536x; 1.0536x over previous
//
#include <hip/hip_runtime.h>
#include <stdint.h>

// FibonacciKAN: y[b,o] = sum_i sum_d F_d(tanh(x[b,i])) * C[i,o,d]
// => y = bias[o] + sum_i (t*W0 + t^2*W1 + t^3*W2 + t^4*W3)[i,o]
// GEMM: M=32768, N=256, K=1024, bf16 MFMA 16x16x32.
//
// R9: K-loop stripped to ds_read_b128 + MFMA + B-prefetch. R4-R8 showed
// gemm pinned at ~45us across all tilings with VALU-busy 3x the static
// estimate — the per-halfstep register af-build (unpack/pow/pack + runtime
// addr chains) is the shared structural element. Now staging computes the
// PACKED A-frags (bf16 powers, MFMA frag order) into LDS per 256-K chunk:
// 2x 64KB double-buffered panels, 4 chunks, XOR(m^kl) bank swizzle (2-way
// = free on both write and read phases). Block 128x256, 512 thr = 8 waves
// (2M x 4N, wave tile 64x64 mt4 x nt4), grid 256, 1 block/CU, 2 w/SIMD.
// Numerics bit-identical to R8 -> absmax 9.766e-4.

typedef short bf16x8 __attribute__((ext_vector_type(8)));
typedef float f32x4 __attribute__((ext_vector_type(4)));
typedef unsigned int u32x4 __attribute__((ext_vector_type(4)));

__device__ __forceinline__ unsigned int pack_bf16_trunc(float a, float b) {
  return __builtin_amdgcn_perm(__float_as_uint(b), __float_as_uint(a), 0x07060302u);
}
__device__ __forceinline__ unsigned int round_bf16_bits(float a) {
  unsigned int u = __float_as_uint(a);
  return u + 0x7fffu + ((u >> 16) & 1u);
}
__device__ __forceinline__ unsigned int pack_bf16_rne(float a, float b) {
  return __builtin_amdgcn_perm(round_bf16_bits(b), round_bf16_bits(a), 0x07060302u);
}
__device__ __forceinline__ float fast_tanh(float x) {
  float e = exp2f(x * 2.8853900817779268f);  // 2*log2(e)
  return 1.0f - 2.0f * __builtin_amdgcn_rcpf(e + 1.0f);
}
// packed (t,t2) and (t3,t4) dwords from x, with t RNE'd to bf16 first
// (identical numerics to the R1-R8 path: powers in f32 from bf16 t, trunc).
__device__ __forceinline__ void powpack(float x, unsigned int* d0,
                                        unsigned int* d1) {
  float t = __uint_as_float(round_bf16_bits(fast_tanh(x)) & 0xffff0000u);
  float t2 = t * t;
  float t3 = t2 * t, t4 = t2 * t2;
  *d0 = pack_bf16_trunc(t, t2);
  *d1 = pack_bf16_trunc(t3, t4);
}

// ---------------- prep (unchanged since R2) ----------------
__global__ void prep_kernel(const float* __restrict__ C, short* __restrict__ Bp,
                            float* __restrict__ bias) {
  int b = blockIdx.x;
  if (b < 256) {
    int i = b;
    int n = threadIdx.x;
    const float* c = C + (i * 256 + n) * 6;
    float c2 = c[2], c3 = c[3], c4_ = c[4], c5 = c[5];
    float w0 = c2 + 2.0f * c4_;
    float w1 = c3 + 3.0f * c5;
    unsigned int r0 = pack_bf16_rne(w0, w1);
    unsigned int r1 = pack_bf16_rne(c4_, c5);
    int ks = i >> 3;
    int lane = (((i >> 1) & 3) << 4) | (n & 15);
    int ntg = n >> 4;
    int off = (((ks * 16 + ntg) * 64 + lane) << 3) + ((i & 1) << 2);
    *(uint2*)(Bp + off) = make_uint2(r0, r1);
  } else {
    int w = threadIdx.x >> 6;
    int t = threadIdx.x & 63;
    int n = (b - 256) * 4 + w;
    float s = 0.0f;
#pragma unroll
    for (int r = 0; r < 4; ++r) {
      int i = t + r * 64;
      const float* c = C + (i * 256 + n) * 6;
      s += c[1] + c[3] + c[5];
    }
#pragma unroll
    for (int off = 32; off > 0; off >>= 1) s += __shfl_down(s, off);
    if (t == 0) bias[n] = s;
  }
}

// ---------------- fused tanh + powers + GEMM ----------------
// LDS A-panel layout (16B units): [panel(2)][rg(8)][kl(8)][lg(4)][m^kl(16)]
// holding A-frag bf16x8 for (block row group rg, chunk-local k-step kl,
// lane=(lg,m)). rg = global_row>>4, element (row, i_rel): kl = i_rel>>3,
// lg = (i_rel>>1)&3, j = (i_rel&1)*4 + p.
__global__ __launch_bounds__(512, 2) void fibkan_gemm(
    const float* __restrict__ x, const short* __restrict__ Bp,
    const float* __restrict__ bias, float* __restrict__ y) {
  __shared__ u32x4 tl16[8192];  // 131072 B -> 1 block/CU
  const int tid = threadIdx.x;
  const int lane = tid & 63;
  const int wv = tid >> 6;          // 0..7
  const int wm = wv >> 2;           // M half (64 rows)
  const int wn = wv & 3;            // N quarter (64 cols)
  const int mb = blockIdx.x;
  const int lhi = lane >> 4, llo = lane & 15;

  const float4* xp = (const float4*)(x) + mb * 128 * 64;  // row = 64 float4

  float bv[4];
#pragma unroll
  for (int nt = 0; nt < 4; ++nt) bv[nt] = bias[wn * 64 + nt * 16 + llo];

  float4 xv[4];
  auto stage_load = [&](int ch) {
#pragma unroll
    for (int it = 0; it < 4; ++it) {
      int j = tid + it * 512;          // 0..2047
      int row = j >> 4, c4 = j & 15;   // 16 float4-cols per chunk
      xv[it] = xp[row * 64 + ch * 16 + c4];
    }
  };
  auto stage_write = [&](int panel) {
#pragma unroll
    for (int it = 0; it < 4; ++it) {
      int j = tid + it * 512;
      int row = j >> 4, c4 = j & 15;
      float4 v = xv[it];
      unsigned int a0, a1, b0, b1, c0, c1, d0, d1;
      powpack(v.x, &a0, &a1);
      powpack(v.y, &b0, &b1);
      powpack(v.z, &c0, &c1);
      powpack(v.w, &d0, &d1);
      int rg = row >> 4, m = row & 15, kl = c4 >> 1;
      int base = panel * 4096 + rg * 512 + kl * 64 + (m ^ kl);
      u32x4 f01 = {a0, a1, b0, b1};  // i_rel = 4c4, 4c4+1
      u32x4 f23 = {c0, c1, d0, d1};  // i_rel = 4c4+2, 4c4+3
      tl16[base + (((2 * c4) & 3) << 4)] = f01;
      tl16[base + (((2 * c4 + 1) & 3) << 4)] = f23;
    }
  };

  // B-frag (ks, nt): bp[ks*1024 + nt*64]; wm-pairs of waves share addresses
  const bf16x8* bp = (const bf16x8*)Bp + (wn * 4) * 64 + lane;

  f32x4 acc[4][4] = {};
  bf16x8 bB[2][4];

  // stage chunk 0 -> panel 0; preload bB pipeline
  stage_load(0);
#pragma unroll
  for (int p = 0; p < 2; ++p)
#pragma unroll
    for (int nt = 0; nt < 4; ++nt) bB[p][nt] = bp[p * 1024 + nt * 64];
  stage_write(0);
  __syncthreads();

  const int abase = wm * 4 * 512 + lhi * 16;  // + mt*512 + kl*64 + (llo^kl)

  auto halfstep = [&](int ks, int p, bool pf) {
    int panel = (ks >> 3) & 1, kl = ks & 7;
    bf16x8 af[4];
#pragma unroll
    for (int mt = 0; mt < 4; ++mt)
      af[mt] = __builtin_bit_cast(
          bf16x8, tl16[panel * 4096 + abase + mt * 512 + kl * 64 + (llo ^ kl)]);
#pragma unroll
    for (int nt = 0; nt < 4; ++nt)
#pragma unroll
      for (int mt = 0; mt < 4; ++mt)
        acc[mt][nt] = __builtin_amdgcn_mfma_f32_16x16x32_bf16(
            af[mt], bB[p][nt], acc[mt][nt], 0, 0, 0);
    if (pf) {
#pragma unroll
      for (int nt = 0; nt < 4; ++nt) bB[p][nt] = bp[(ks + 2) * 1024 + nt * 64];
    }
  };

#pragma unroll
  for (int c = 0; c < 4; ++c) {
    if (c < 3) stage_load(c + 1);  // global loads in flight across compute
#pragma unroll
    for (int kl = 0; kl < 8; ++kl) {
      int ks = c * 8 + kl;
      halfstep(ks, ks & 1, ks < 30);
    }
    if (c < 3) {
      stage_write((c + 1) & 1);  // disjoint panel; no barrier before writes
      __syncthreads();
    }
  }

  // epilogue: D col = wn*64 + nt*16 + llo, row = wm*64 + mt*16 + lhi*4 + r
  const int col0 = wn * 64 + llo;
  const int row0 = mb * 128 + wm * 64 + lhi * 4;
#pragma unroll
  for (int nt = 0; nt < 4; ++nt) {
#pragma unroll
    for (int mt = 0; mt < 4; ++mt) {
#pragma unroll
      for (int r = 0; r < 4; ++r) {
        y[(row0 + mt * 16 + r) * 256 + col0 + nt * 16] = acc[mt][nt][r] + bv[nt];
      }
    }
  }
}

extern "C" void kernel_launch(void* const* d_in, const int* in_sizes, int n_in,
                              void* d_out, int out_size, void* d_ws, size_t ws_size,
                              hipStream_t stream) {
  const float* x = (const float*)d_in[0];        // [32768, 256] f32
  const float* C = (const float*)d_in[1];        // [256, 256, 6] f32
  float* y = (float*)d_out;                      // [32768, 256] f32
  float* bias = (float*)d_ws;                    // 256 f32
  short* Bp = (short*)((char*)d_ws + 1024);      // 1024x256 bf16, frag-ordered
  prep_kernel<<<320, 256, 0, stream>>>(C, Bp, bias);
  fibkan_gemm<<<256, 512, 0, stream>>>(x, Bp, bias, y);
}